// Round 19
// baseline (53.063 us; speedup 1.0000x reference)
//
#include <hip/hip_runtime.h>

// LLR denoiser — R19: precombined-W apply + zs/apply batch pipelining.
//   zs_body:    per patch p, S_p = alpha_p*Zhat_p (~THS*G^{-1/2}) via
//               register Newton-Schulz (8 patches per 512-thr block).
//   apply_body: quarter strip (4 rows x 128 px = 32 cells). R18 gather
//               (33 f32 rowsum slots) -> precombine per-cell W (bf16-packed,
//               ONE copy) -> matvec reads 32 uint4/thread (was 128; the
//               R18 LDS-read pipe was ~20us/CU, the dominant pile term).
//   Launches:   zs(b0) ; fused{ apply(b0) || zs(b1) } ; apply(b1)
//               (disjoint pipes: zs = TA/MFMA, apply = LDS + linear I/O).

#define NBATCH  2
#define NCH     16
#define HDIM    512
#define WDIM    512
#define NPH     127
#define NPW     127
#define NPB     (NPH * NPW)            // 16129 patches per batch
#define NCELL   128
#define THS     0.1f
#define NSIT    8

#define ZS8_NBLK ((NPB + 7) / 8)       // 2017 blocks (8 patches each)
#define APQ_NBLK (NCELL * 4)           // 512 quarter-strips per batch

typedef short bf16x8 __attribute__((ext_vector_type(8)));
typedef float f32x4  __attribute__((ext_vector_type(4)));

#define MFMA(a,b,c) __builtin_amdgcn_mfma_f32_16x16x32_bf16((a),(b),(c),0,0,0)

static __device__ inline short f2bf(float x) {
  return __builtin_bit_cast(short, (__bf16)x);   // native RNE convert
}
static __device__ inline float blo2f(unsigned int v) {
  return __builtin_bit_cast(float, v << 16);
}
static __device__ inline float bhi2f(unsigned int v) {
  return __builtin_bit_cast(float, v & 0xffff0000u);
}
static __device__ inline unsigned int pack2bf(float lo, float hi) {
  unsigned int a = (unsigned short)f2bf(lo);
  unsigned int b = (unsigned short)f2bf(hi);
  return (b << 16) | a;
}

// bijective XCD swizzle (m204)
static __device__ inline int xcd_swz(int b, int nwg) {
  const int q = nwg >> 3, r = nwg & 7;
  const int x = b & 7, lo = b >> 3;
  return (x < r ? x * (q + 1) : r * (q + 1) + (x - r) * q) + lo;
}

static __device__ inline bf16x8 fragc(f32x4 v) {
  // symmetric-matrix C-layout -> MFMA A/B fragment (16 nonzero k-slots)
  bf16x8 r;
  r[0] = f2bf(v[0]); r[1] = f2bf(v[1]); r[2] = f2bf(v[2]); r[3] = f2bf(v[3]);
  r[4] = 0; r[5] = 0; r[6] = 0; r[7] = 0;
  return r;
}

// ---------------- zs body: 8 patches per 512-thread block ------------------
static __device__ void zs_body(const float* __restrict__ x,
                               uint2* __restrict__ zs,
                               int zblk, int bi, int t) {
  const int blk = xcd_swz(zblk, ZS8_NBLK);
  const int pr  = blk * 8 + (t >> 6);          // one wave per patch
  if (pr >= NPB) return;
  const int pid = bi * NPB + pr;
  const int ph  = pr / NPW, pw = pr % NPW;
  const int h0  = ph * 4, w0 = pw * 4;
  const int l   = t & 63;
  const int j   = l & 15;
  const int u   = l >> 4;

  const size_t HW = (size_t)HDIM * WDIM;
  const float* xb = x + (size_t)bi * NCH * HW;

  const float* pb = xb + (size_t)j * HW + (size_t)h0 * WDIM + w0;
  const int dh0 = (u >> 1), dw0 = 4 * (u & 1);
  float4 q0 = *(const float4*)(pb + (size_t)(dh0 + 0) * WDIM + dw0);
  float4 q1 = *(const float4*)(pb + (size_t)(dh0 + 2) * WDIM + dw0);
  float4 q2 = *(const float4*)(pb + (size_t)(dh0 + 4) * WDIM + dw0);
  float4 q3 = *(const float4*)(pb + (size_t)(dh0 + 6) * WDIM + dw0);

  bf16x8 m0, m1;
  m0[0]=f2bf(q0.x); m0[1]=f2bf(q0.y); m0[2]=f2bf(q0.z); m0[3]=f2bf(q0.w);
  m0[4]=f2bf(q1.x); m0[5]=f2bf(q1.y); m0[6]=f2bf(q1.z); m0[7]=f2bf(q1.w);
  m1[0]=f2bf(q2.x); m1[1]=f2bf(q2.y); m1[2]=f2bf(q2.z); m1[3]=f2bf(q2.w);
  m1[4]=f2bf(q3.x); m1[5]=f2bf(q3.y); m1[6]=f2bf(q3.z); m1[7]=f2bf(q3.w);

  f32x4 g = {0.f, 0.f, 0.f, 0.f};
  g = MFMA(m0, m0, g);
  g = MFMA(m1, m1, g);

  float s2 = g[0]*g[0] + g[1]*g[1] + g[2]*g[2] + g[3]*g[3];
  #pragma unroll
  for (int m = 32; m >= 1; m >>= 1) s2 += __shfl_xor(s2, m, 64);

  uint2 wv = {0u, 0u};
  if (s2 > 1e-20f) {
    const float invf  = rsqrtf(s2);
    const float gsc   = 2.0f * invf;           // normalize by t = f/2
    const float alpha = THS * sqrtf(gsc);

    f32x4 Yc, Zc;
    #pragma unroll
    for (int r = 0; r < 4; ++r) {
      Yc[r] = g[r] * gsc;
      Zc[r] = (4 * u + r == j) ? 1.0f : 0.0f;
    }

    const f32x4 zero = {0.f, 0.f, 0.f, 0.f};
    for (int it = 0; it < NSIT - 1; ++it) {
      bf16x8 yF = fragc(Yc), zF = fragc(Zc);
      f32x4 tt = MFMA(zF, yF, zero);
      bf16x8 tF = fragc(tt);
      f32x4 py = MFMA(yF, tF, zero);
      f32x4 pz = MFMA(tF, zF, zero);
      #pragma unroll
      for (int r = 0; r < 4; ++r) {
        Yc[r] = 1.5f * Yc[r] - 0.5f * py[r];
        Zc[r] = 1.5f * Zc[r] - 0.5f * pz[r];
      }
    }
    {
      bf16x8 yF = fragc(Yc), zF = fragc(Zc);
      f32x4 tt = MFMA(zF, yF, zero);
      bf16x8 tF = fragc(tt);
      f32x4 pz = MFMA(tF, zF, zero);
      #pragma unroll
      for (int r = 0; r < 4; ++r) Zc[r] = 1.5f * Zc[r] - 0.5f * pz[r];
    }

    wv.x = pack2bf(alpha * Zc[0], alpha * Zc[1]);
    wv.y = pack2bf(alpha * Zc[2], alpha * Zc[3]);
  }
  zs[(size_t)pid * 64 + l] = wv;               // coalesced 512B per patch
}

// ---------------- apply body: quarter strip, precombined W -----------------
// abid = ci*4 + qs (within batch bi). 512 threads.
// RS slot layout (R18, verified): RS[s*260 + 16*o + i] = rowsum_s[o][i]
//   (o = out-ch, i = in-ch); slot s -> patch col pw = qs*32 - 1 + s.
// PW layout: PW[c*132 + 16*m + i] = pack(W_c[2m][i], W_c[2m+1][i]),
//   W_c = (RS[c] + RS[c+1]) summed f32 then rounded once to bf16.
static __device__ void apply_body(const float* __restrict__ x,
                                  const uint2* __restrict__ zs,
                                  float* __restrict__ out,
                                  float* RS, unsigned int* PW,
                                  int abid, int bi, int t) {
  const int qs  = abid & 3;
  const int ci  = abid >> 2;                   // 0..127
  const int r   = t >> 7;                      // pixel row 0..3
  const int px  = t & 127;                     // pixel col in quarter
  const int c   = px >> 2;                     // cell-local 0..31

  const size_t HW = (size_t)HDIM * WDIM;
  const int h   = 4 * ci + r;
  const int wpx = qs * 128 + px;
  const float* xp = x + (size_t)bi * NCH * HW + (size_t)h * WDIM + wpx;

  // ---- prefetch x: 16 coalesced 256B loads (in flight across the gather)
  float xv[16];
  #pragma unroll
  for (int e = 0; e < 16; ++e) xv[e] = xp[(size_t)e * HW];

  // ---- gather: 33 f32 rowsum slots -> RS (R18 verbatim)
  {
    const int w8 = t >> 6;                     // wave 0..7
    const int l  = t & 63;
    const int u  = l >> 4, j = l & 15;
    const uint2* zb = zs + (size_t)bi * NPB * 64;
    const bool vh0 = (ci > 0), vh1 = (ci < NPH);
    const int ph0c = vh0 ? ci - 1 : 0;
    const int ph1c = vh1 ? ci : NPH - 1;
    for (int s = w8; s < 33; s += 8) {
      const int pw = qs * 32 - 1 + s;
      const bool vw = ((unsigned)pw <= (unsigned)(NPW - 1));
      const int pwc = vw ? pw : 0;
      uint2 z0 = zb[((size_t)ph0c * NPW + pwc) * 64 + l];
      uint2 z1 = zb[((size_t)ph1c * NPW + pwc) * 64 + l];
      if (!(vw && vh0)) { z0.x = 0u; z0.y = 0u; }
      if (!(vw && vh1)) { z1.x = 0u; z1.y = 0u; }
      float* rs = &RS[s * 260 + j];
      rs[16 * (4 * u + 0)] = blo2f(z0.x) + blo2f(z1.x);
      rs[16 * (4 * u + 1)] = bhi2f(z0.x) + bhi2f(z1.x);
      rs[16 * (4 * u + 2)] = blo2f(z0.y) + blo2f(z1.y);
      rs[16 * (4 * u + 3)] = bhi2f(z0.y) + bhi2f(z1.y);
    }
  }
  __syncthreads();

  // ---- precombine: per-cell W = RS[c] + RS[c+1], bf16-pair packed
  {
    const int cc = t >> 4, j = t & 15;         // cc 0..31, j = in-ch
    #pragma unroll
    for (int m = 0; m < 8; ++m) {              // out-ch pair (2m, 2m+1)
      const float lo = RS[cc * 260 + 32 * m + j]
                     + RS[(cc + 1) * 260 + 32 * m + j];
      const float hi = RS[cc * 260 + 32 * m + 16 + j]
                     + RS[(cc + 1) * 260 + 32 * m + 16 + j];
      PW[cc * 132 + 16 * m + j] = pack2bf(lo, hi);
    }
  }
  __syncthreads();

  // ---- matvec: out = x - W*x/cnt   (32 uint4 LDS reads, was 128)
  const int cj = qs * 32 + c;
  const float cnth = 2.0f - (ci == 0) - (ci == NCELL - 1);
  const float cntw = 2.0f - (cj == 0) - (cj == NCELL - 1);
  const float sc = 1.0f / (cnth * cntw);

  float acc[16];
  #pragma unroll
  for (int co = 0; co < 16; ++co) acc[co] = 0.f;
  #pragma unroll
  for (int p = 0; p < 8; ++p) {
    #pragma unroll
    for (int k = 0; k < 4; ++k) {
      const uint4 V = *(const uint4*)&PW[c * 132 + 16 * p + 4 * k];
      const unsigned int vv[4] = {V.x, V.y, V.z, V.w};
      #pragma unroll
      for (int e2 = 0; e2 < 4; ++e2) {
        const int e = 4 * k + e2;
        acc[2 * p]     += blo2f(vv[e2]) * xv[e];
        acc[2 * p + 1] += bhi2f(vv[e2]) * xv[e];
      }
    }
  }

  float* po = out + (size_t)bi * NCH * HW + (size_t)h * WDIM + wpx;
  #pragma unroll
  for (int co = 0; co < 16; ++co)
    po[(size_t)co * HW] = xv[co] - sc * acc[co];
}

// ---------------- kernels ---------------------------------------------------
__global__ __launch_bounds__(512, 6) void llr_zs8(const float* __restrict__ x,
                                                  uint2* __restrict__ zs,
                                                  int bi) {
  zs_body(x, zs, blockIdx.x, bi, threadIdx.x);
}

__global__ __launch_bounds__(512, 6) void llr_ap(const float* __restrict__ x,
                                                 const uint2* __restrict__ zs,
                                                 float* __restrict__ out,
                                                 int bi) {
  __shared__ float RS[33 * 260];               // 34.3 KB
  __shared__ unsigned int PW[32 * 132];        // 16.9 KB
  apply_body(x, zs, out, RS, PW, blockIdx.x, bi, threadIdx.x);
}

// fused: blocks [0, APQ_NBLK) = apply(batch0); rest = zs(batch1).
// APQ_NBLK = 512 is divisible by 8, so the zs part's XCD swizzle (zi mod 8
// == bid mod 8) remains valid under the dispatch interleave.
__global__ __launch_bounds__(512, 6) void llr_fused(const float* __restrict__ x,
                                                    uint2* __restrict__ zs,
                                                    float* __restrict__ out) {
  __shared__ float RS[33 * 260];
  __shared__ unsigned int PW[32 * 132];
  const int bid = blockIdx.x;
  if (bid < APQ_NBLK) {
    apply_body(x, zs, out, RS, PW, bid, 0, threadIdx.x);
  } else {
    zs_body(x, zs, bid - APQ_NBLK, 1, threadIdx.x);
  }
}

extern "C" void kernel_launch(void* const* d_in, const int* in_sizes, int n_in,
                              void* d_out, int out_size, void* d_ws, size_t ws_size,
                              hipStream_t stream) {
  const float* x = (const float*)d_in[0];
  float* out = (float*)d_out;
  uint2* zs = (uint2*)d_ws;                    // 32258*512B = 16.5 MB

  llr_zs8<<<dim3(ZS8_NBLK), dim3(512), 0, stream>>>(x, zs, 0);
  llr_fused<<<dim3(APQ_NBLK + ZS8_NBLK), dim3(512), 0, stream>>>(x, zs, out);
  llr_ap<<<dim3(APQ_NBLK), dim3(512), 0, stream>>>(x, zs, out, 1);
}

// Round 20
// 47.041 us; speedup vs baseline: 1.1280x; 1.1280x over previous
//
#include <hip/hip_runtime.h>

// LLR denoiser, two-phase, atomic-free:
//   Phase 1 (llr_zs): per patch p, S_p = alpha_p * Zhat_p (16x16 ~ THS*G^{-1/2})
//            via register-resident Newton-Schulz; bf16 to ws. XCD-swizzled.
//   Phase 2 (llr_q): quarter-strip (4 rows x 128 px = 32 cells), 512 thr.
//            R20 fix: x loads moved AFTER the barrier. __syncthreads drains
//            vmcnt(0), so a pre-barrier x-prefetch makes every wave wait on
//            ALL ~9000 outstanding lines of the block (tail-latency
//            amplification) — present in every 35-43us variant, absent in
//            the 10us cpy_strip. Phase B is now cpy_strip + LDS-broadcast
//            FMAs, wave-locally pipelined.

#define NBATCH  2
#define NCH     16
#define HDIM    512
#define WDIM    512
#define NPH     127
#define NPW     127
#define NPATCH  (NBATCH * NPH * NPW)
#define NCELL   128
#define THS     0.1f
#define NSIT    7

typedef short bf16x8 __attribute__((ext_vector_type(8)));
typedef float f32x4  __attribute__((ext_vector_type(4)));

#define MFMA(a,b,c) __builtin_amdgcn_mfma_f32_16x16x32_bf16((a),(b),(c),0,0,0)

static __device__ inline short f2bf(float x) {
  return __builtin_bit_cast(short, (__bf16)x);   // native RNE convert
}
static __device__ inline float blo2f(unsigned int v) {
  return __builtin_bit_cast(float, v << 16);
}
static __device__ inline float bhi2f(unsigned int v) {
  return __builtin_bit_cast(float, v & 0xffff0000u);
}
static __device__ inline unsigned int pack2bf(float lo, float hi) {
  unsigned int a = (unsigned short)f2bf(lo);
  unsigned int b = (unsigned short)f2bf(hi);
  return (b << 16) | a;
}

// bijective XCD swizzle (m204) — used by llr_zs only
static __device__ inline int xcd_swz(int b, int nwg) {
  const int q = nwg >> 3, r = nwg & 7;
  const int x = b & 7, lo = b >> 3;
  return (x < r ? x * (q + 1) : r * (q + 1) + (x - r) * q) + lo;
}

static __device__ inline bf16x8 fragc(f32x4 v) {
  // symmetric-matrix C-layout -> MFMA A/B fragment (16 nonzero k-slots)
  bf16x8 r;
  r[0] = f2bf(v[0]); r[1] = f2bf(v[1]); r[2] = f2bf(v[2]); r[3] = f2bf(v[3]);
  r[4] = 0; r[5] = 0; r[6] = 0; r[7] = 0;
  return r;
}

// ---------------- Phase 1: per-patch scaled inverse-sqrt matrices ----------
#define ZS_NBLK ((NPATCH + 3) / 4)
__global__ __launch_bounds__(256) void llr_zs(const float* __restrict__ x,
                                              uint2* __restrict__ zs) {
  const int blk = xcd_swz(blockIdx.x, ZS_NBLK);
  const int pid = blk * 4 + (threadIdx.x >> 6);  // one wave per patch
  if (pid >= NPATCH) return;
  const int bi  = pid / (NPH * NPW);
  const int pr  = pid % (NPH * NPW);
  const int ph  = pr / NPW, pw = pr % NPW;
  const int h0  = ph * 4, w0 = pw * 4;
  const int l   = threadIdx.x & 63;
  const int j   = l & 15;
  const int u   = l >> 4;

  const size_t HW = (size_t)HDIM * WDIM;
  const float* xb = x + (size_t)bi * NCH * HW;

  const float* pb = xb + (size_t)j * HW + (size_t)h0 * WDIM + w0;
  const int dh0 = (u >> 1), dw0 = 4 * (u & 1);
  float4 q0 = *(const float4*)(pb + (size_t)(dh0 + 0) * WDIM + dw0);
  float4 q1 = *(const float4*)(pb + (size_t)(dh0 + 2) * WDIM + dw0);
  float4 q2 = *(const float4*)(pb + (size_t)(dh0 + 4) * WDIM + dw0);
  float4 q3 = *(const float4*)(pb + (size_t)(dh0 + 6) * WDIM + dw0);

  bf16x8 m0, m1;
  m0[0]=f2bf(q0.x); m0[1]=f2bf(q0.y); m0[2]=f2bf(q0.z); m0[3]=f2bf(q0.w);
  m0[4]=f2bf(q1.x); m0[5]=f2bf(q1.y); m0[6]=f2bf(q1.z); m0[7]=f2bf(q1.w);
  m1[0]=f2bf(q2.x); m1[1]=f2bf(q2.y); m1[2]=f2bf(q2.z); m1[3]=f2bf(q2.w);
  m1[4]=f2bf(q3.x); m1[5]=f2bf(q3.y); m1[6]=f2bf(q3.z); m1[7]=f2bf(q3.w);

  f32x4 g = {0.f, 0.f, 0.f, 0.f};
  g = MFMA(m0, m0, g);
  g = MFMA(m1, m1, g);

  float s2 = g[0]*g[0] + g[1]*g[1] + g[2]*g[2] + g[3]*g[3];
  #pragma unroll
  for (int m = 32; m >= 1; m >>= 1) s2 += __shfl_xor(s2, m, 64);

  uint2 wv = {0u, 0u};
  if (s2 > 1e-20f) {
    const float invf  = rsqrtf(s2);
    const float gsc   = 2.0f * invf;           // normalize by t = f/2
    const float alpha = THS * sqrtf(gsc);

    f32x4 Yc, Zc;
    #pragma unroll
    for (int r = 0; r < 4; ++r) {
      Yc[r] = g[r] * gsc;
      Zc[r] = (4 * u + r == j) ? 1.0f : 0.0f;
    }

    const f32x4 zero = {0.f, 0.f, 0.f, 0.f};
    for (int it = 0; it < NSIT - 1; ++it) {
      bf16x8 yF = fragc(Yc), zF = fragc(Zc);
      f32x4 t  = MFMA(zF, yF, zero);
      bf16x8 tF = fragc(t);
      f32x4 py = MFMA(yF, tF, zero);
      f32x4 pz = MFMA(tF, zF, zero);
      #pragma unroll
      for (int r = 0; r < 4; ++r) {
        Yc[r] = 1.5f * Yc[r] - 0.5f * py[r];
        Zc[r] = 1.5f * Zc[r] - 0.5f * pz[r];
      }
    }
    {
      bf16x8 yF = fragc(Yc), zF = fragc(Zc);
      f32x4 t  = MFMA(zF, yF, zero);
      bf16x8 tF = fragc(t);
      f32x4 pz = MFMA(tF, zF, zero);
      #pragma unroll
      for (int r = 0; r < 4; ++r) Zc[r] = 1.5f * Zc[r] - 0.5f * pz[r];
    }

    wv.x = pack2bf(alpha * Zc[0], alpha * Zc[1]);
    wv.y = pack2bf(alpha * Zc[2], alpha * Zc[3]);
  }
  zs[(size_t)pid * 64 + l] = wv;
}

// ---------------- Phase 2: quarter-strip apply (R18, x-load AFTER barrier) -
// Block = (bi, ci, qs): 4 rows x 128 px = 32 cells. 512 threads:
//   thread t: r = t>>7 (pixel row), px = t&127, cell c = px>>2.
//   Wave = 64 consecutive px = 16 cells x 4 lanes -> RS reads broadcast x4,
//   rows at banks 4c%32 -> worst 2-way (free).
// Gather: 33 f32 rowsum slots (pw = qs*32-1+s); slot s by wave s%8; each
//   slot = 2 coalesced uint2 zs loads summed -> f32, scattered b32 writes.
// LDS slot layout: RS[s*260 + 16*co + ci_]; pitch 260 keeps float4 aligned.
#define Q_NBLK (NBATCH * NCELL * 4)   // 1024 -> 4 blocks/CU
__global__ __launch_bounds__(512, 8) void llr_q(const float* __restrict__ x,
                                                const uint2* __restrict__ zs,
                                                float* __restrict__ out) {
  __shared__ float RS[33 * 260];               // 34.3 KB

  const int bid = blockIdx.x;                  // bi*512 + ci*4 + qs
  const int qs  = bid & 3;
  const int ci  = (bid >> 2) & 127;
  const int bi  = bid >> 9;
  const int t   = threadIdx.x;
  const int r   = t >> 7;                      // pixel row 0..3
  const int px  = t & 127;                     // pixel col within quarter
  const int c   = px >> 2;                     // cell-local 0..31

  const size_t HW = (size_t)HDIM * WDIM;
  const int h   = 4 * ci + r;
  const int wpx = qs * 128 + px;

  // ---- gather: 33 f32 rowsum slots -> LDS  (ONLY these loads cross the
  //      barrier's vmcnt(0) drain — no x-prefetch coupled to it)
  {
    const int w8 = t >> 6;                     // wave 0..7
    const int l  = t & 63;
    const int u  = l >> 4, j = l & 15;
    const uint2* zb = zs + (size_t)bi * NPH * NPW * 64;
    const bool vh0 = (ci > 0), vh1 = (ci < NPH);
    const int ph0c = vh0 ? ci - 1 : 0;
    const int ph1c = vh1 ? ci : NPH - 1;
    for (int s = w8; s < 33; s += 8) {
      const int pw = qs * 32 - 1 + s;
      const bool vw = ((unsigned)pw <= (unsigned)(NPW - 1));
      const int pwc = vw ? pw : 0;
      uint2 z0 = zb[((size_t)ph0c * NPW + pwc) * 64 + l];
      uint2 z1 = zb[((size_t)ph1c * NPW + pwc) * 64 + l];
      if (!(vw && vh0)) { z0.x = 0u; z0.y = 0u; }
      if (!(vw && vh1)) { z1.x = 0u; z1.y = 0u; }
      float* rs = &RS[s * 260 + j];
      rs[16 * (4 * u + 0)] = blo2f(z0.x) + blo2f(z1.x);
      rs[16 * (4 * u + 1)] = bhi2f(z0.x) + bhi2f(z1.x);
      rs[16 * (4 * u + 2)] = blo2f(z0.y) + blo2f(z1.y);
      rs[16 * (4 * u + 3)] = bhi2f(z0.y) + bhi2f(z1.y);
    }
  }
  __syncthreads();

  // ---- phase B: load x NOW (wave-local pipelining, cpy_strip-like), matvec
  const float* xp = x + (size_t)bi * NCH * HW + (size_t)h * WDIM + wpx;
  float xv[16];
  #pragma unroll
  for (int e = 0; e < 16; ++e) xv[e] = xp[(size_t)e * HW];

  const int cj = qs * 32 + c;                  // global cell col
  const float cnth = 2.0f - (ci == 0) - (ci == NCELL - 1);
  const float cntw = 2.0f - (cj == 0) - (cj == NCELL - 1);
  const float sc = 1.0f / (cnth * cntw);

  const float* rsA = &RS[c * 260];
  const float* rsB = &RS[(c + 1) * 260];
  float* po = out + (size_t)bi * NCH * HW + (size_t)h * WDIM + wpx;
  #pragma unroll
  for (int co = 0; co < 16; ++co) {
    float acc = 0.f;
    #pragma unroll
    for (int k = 0; k < 4; ++k) {
      const float4 A = *(const float4*)(rsA + 16 * co + 4 * k);  // broadcast x4
      const float4 B = *(const float4*)(rsB + 16 * co + 4 * k);
      acc += (A.x + B.x) * xv[4 * k + 0];
      acc += (A.y + B.y) * xv[4 * k + 1];
      acc += (A.z + B.z) * xv[4 * k + 2];
      acc += (A.w + B.w) * xv[4 * k + 3];
    }
    po[(size_t)co * HW] = xv[co] - sc * acc;   // 256B contiguous per instr
  }
}

extern "C" void kernel_launch(void* const* d_in, const int* in_sizes, int n_in,
                              void* d_out, int out_size, void* d_ws, size_t ws_size,
                              hipStream_t stream) {
  const float* x = (const float*)d_in[0];
  float* out = (float*)d_out;
  uint2* zs = (uint2*)d_ws;                    // 32258*512B = 16.5 MB

  llr_zs<<<dim3(ZS_NBLK), dim3(256), 0, stream>>>(x, zs);
  llr_q<<<dim3(Q_NBLK), dim3(512), 0, stream>>>(x, zs, out);
}

// Round 21
// 44.896 us; speedup vs baseline: 1.1819x; 1.0478x over previous
//
#include <hip/hip_runtime.h>

// LLR denoiser, two-phase, atomic-free:
//   Phase 1 (llr_zs): per patch p, S_p = alpha_p * Zhat_p (16x16 ~ THS*G^{-1/2})
//            via register-resident Newton-Schulz; bf16 to ws. XCD-swizzled.
//   Phase 2 (llr_q2): quarter-strip (4 rows x 128 px = 32 cells), 512 thr.
//            R21: matvec LDS reads cut 4x (128 -> 32 uint4/thread) by having
//            the GATHER write final per-cell W (4 masked zs loads, f32 sum,
//            1/cnt folded, bf16-pair packed) straight to LDS. One barrier,
//            16.9 KB LDS, no intermediate rowsum buffer (R19's gain without
//            its confounds: extra barrier, re-pack phase, 51KB LDS).

#define NBATCH  2
#define NCH     16
#define HDIM    512
#define WDIM    512
#define NPH     127
#define NPW     127
#define NPATCH  (NBATCH * NPH * NPW)
#define NCELL   128
#define THS     0.1f
#define NSIT    7

typedef short bf16x8 __attribute__((ext_vector_type(8)));
typedef float f32x4  __attribute__((ext_vector_type(4)));

#define MFMA(a,b,c) __builtin_amdgcn_mfma_f32_16x16x32_bf16((a),(b),(c),0,0,0)

static __device__ inline short f2bf(float x) {
  return __builtin_bit_cast(short, (__bf16)x);   // native RNE convert
}
static __device__ inline float blo2f(unsigned int v) {
  return __builtin_bit_cast(float, v << 16);
}
static __device__ inline float bhi2f(unsigned int v) {
  return __builtin_bit_cast(float, v & 0xffff0000u);
}
static __device__ inline unsigned int pack2bf(float lo, float hi) {
  unsigned int a = (unsigned short)f2bf(lo);
  unsigned int b = (unsigned short)f2bf(hi);
  return (b << 16) | a;
}

// bijective XCD swizzle (m204) — used by llr_zs only
static __device__ inline int xcd_swz(int b, int nwg) {
  const int q = nwg >> 3, r = nwg & 7;
  const int x = b & 7, lo = b >> 3;
  return (x < r ? x * (q + 1) : r * (q + 1) + (x - r) * q) + lo;
}

static __device__ inline bf16x8 fragc(f32x4 v) {
  // symmetric-matrix C-layout -> MFMA A/B fragment (16 nonzero k-slots)
  bf16x8 r;
  r[0] = f2bf(v[0]); r[1] = f2bf(v[1]); r[2] = f2bf(v[2]); r[3] = f2bf(v[3]);
  r[4] = 0; r[5] = 0; r[6] = 0; r[7] = 0;
  return r;
}

// ---------------- Phase 1: per-patch scaled inverse-sqrt matrices ----------
#define ZS_NBLK ((NPATCH + 3) / 4)
__global__ __launch_bounds__(256) void llr_zs(const float* __restrict__ x,
                                              uint2* __restrict__ zs) {
  const int blk = xcd_swz(blockIdx.x, ZS_NBLK);
  const int pid = blk * 4 + (threadIdx.x >> 6);  // one wave per patch
  if (pid >= NPATCH) return;
  const int bi  = pid / (NPH * NPW);
  const int pr  = pid % (NPH * NPW);
  const int ph  = pr / NPW, pw = pr % NPW;
  const int h0  = ph * 4, w0 = pw * 4;
  const int l   = threadIdx.x & 63;
  const int j   = l & 15;
  const int u   = l >> 4;

  const size_t HW = (size_t)HDIM * WDIM;
  const float* xb = x + (size_t)bi * NCH * HW;

  const float* pb = xb + (size_t)j * HW + (size_t)h0 * WDIM + w0;
  const int dh0 = (u >> 1), dw0 = 4 * (u & 1);
  float4 q0 = *(const float4*)(pb + (size_t)(dh0 + 0) * WDIM + dw0);
  float4 q1 = *(const float4*)(pb + (size_t)(dh0 + 2) * WDIM + dw0);
  float4 q2 = *(const float4*)(pb + (size_t)(dh0 + 4) * WDIM + dw0);
  float4 q3 = *(const float4*)(pb + (size_t)(dh0 + 6) * WDIM + dw0);

  bf16x8 m0, m1;
  m0[0]=f2bf(q0.x); m0[1]=f2bf(q0.y); m0[2]=f2bf(q0.z); m0[3]=f2bf(q0.w);
  m0[4]=f2bf(q1.x); m0[5]=f2bf(q1.y); m0[6]=f2bf(q1.z); m0[7]=f2bf(q1.w);
  m1[0]=f2bf(q2.x); m1[1]=f2bf(q2.y); m1[2]=f2bf(q2.z); m1[3]=f2bf(q2.w);
  m1[4]=f2bf(q3.x); m1[5]=f2bf(q3.y); m1[6]=f2bf(q3.z); m1[7]=f2bf(q3.w);

  f32x4 g = {0.f, 0.f, 0.f, 0.f};
  g = MFMA(m0, m0, g);
  g = MFMA(m1, m1, g);

  float s2 = g[0]*g[0] + g[1]*g[1] + g[2]*g[2] + g[3]*g[3];
  #pragma unroll
  for (int m = 32; m >= 1; m >>= 1) s2 += __shfl_xor(s2, m, 64);

  uint2 wv = {0u, 0u};
  if (s2 > 1e-20f) {
    const float invf  = rsqrtf(s2);
    const float gsc   = 2.0f * invf;           // normalize by t = f/2
    const float alpha = THS * sqrtf(gsc);

    f32x4 Yc, Zc;
    #pragma unroll
    for (int r = 0; r < 4; ++r) {
      Yc[r] = g[r] * gsc;
      Zc[r] = (4 * u + r == j) ? 1.0f : 0.0f;
    }

    const f32x4 zero = {0.f, 0.f, 0.f, 0.f};
    for (int it = 0; it < NSIT - 1; ++it) {
      bf16x8 yF = fragc(Yc), zF = fragc(Zc);
      f32x4 t  = MFMA(zF, yF, zero);
      bf16x8 tF = fragc(t);
      f32x4 py = MFMA(yF, tF, zero);
      f32x4 pz = MFMA(tF, zF, zero);
      #pragma unroll
      for (int r = 0; r < 4; ++r) {
        Yc[r] = 1.5f * Yc[r] - 0.5f * py[r];
        Zc[r] = 1.5f * Zc[r] - 0.5f * pz[r];
      }
    }
    {
      bf16x8 yF = fragc(Yc), zF = fragc(Zc);
      f32x4 t  = MFMA(zF, yF, zero);
      bf16x8 tF = fragc(t);
      f32x4 pz = MFMA(tF, zF, zero);
      #pragma unroll
      for (int r = 0; r < 4; ++r) Zc[r] = 1.5f * Zc[r] - 0.5f * pz[r];
    }

    wv.x = pack2bf(alpha * Zc[0], alpha * Zc[1]);
    wv.y = pack2bf(alpha * Zc[2], alpha * Zc[3]);
  }
  zs[(size_t)pid * 64 + l] = wv;
}

// ---------------- Phase 2: quarter-strip apply, direct packed W ------------
// Block = (bi, ci, qs): 4 rows x 128 px = 32 cells. 512 threads.
// Gather: wave w8 owns cells cc = w8 + 8*round (4 rounds). Per cell:
//   4 masked coalesced uint2 zs loads (2 patch rows x 2 cols), f32 sum,
//   1/cnt folded, bf16-pair packed:
//     lane (u = l>>4, j = l&15) holds rows 4u..4u+3, col j ->
//     PW[cc*132 + 16*(2u)   + j] = pack(W[4u+0][j], W[4u+1][j])
//     PW[cc*132 + 16*(2u+1) + j] = pack(W[4u+2][j], W[4u+3][j])
// Matvec: thread cell c reads 32 uint4 (4-lane broadcast; banks 4c%32 ->
//   2-way = free), unpacks, 256 FMAs; out = x - acc (scale pre-folded).
#define Q_NBLK (NBATCH * NCELL * 4)   // 1024 -> 4 blocks/CU
__global__ __launch_bounds__(512, 8) void llr_q2(const float* __restrict__ x,
                                                 const uint2* __restrict__ zs,
                                                 float* __restrict__ out) {
  __shared__ unsigned int PW[32 * 132];        // 16.9 KB

  const int bid = blockIdx.x;                  // bi*512 + ci*4 + qs
  const int qs  = bid & 3;
  const int ci  = (bid >> 2) & 127;
  const int bi  = bid >> 9;
  const int t   = threadIdx.x;
  const int r   = t >> 7;                      // pixel row 0..3
  const int px  = t & 127;                     // pixel col within quarter
  const int c   = px >> 2;                     // cell-local 0..31

  const size_t HW = (size_t)HDIM * WDIM;
  const int h   = 4 * ci + r;
  const int wpx = qs * 128 + px;

  // ---- gather: per-cell packed W -> LDS (4 cells per wave, 4 loads each)
  {
    const int w8 = t >> 6;                     // wave 0..7
    const int l  = t & 63;
    const int u  = l >> 4, j = l & 15;
    const uint2* zb = zs + (size_t)bi * NPH * NPW * 64;
    const bool vh0 = (ci > 0), vh1 = (ci < NPH);
    const int ph0c = vh0 ? ci - 1 : 0;
    const int ph1c = vh1 ? ci : NPH - 1;
    const float cnth = 2.0f - (ci == 0) - (ci == NCELL - 1);
    #pragma unroll
    for (int rd = 0; rd < 4; ++rd) {
      const int cc = rd * 8 + w8;              // cell 0..31 (wave-uniform)
      const int cj = qs * 32 + cc;             // global cell col
      const int pwl = cj - 1, pwr = cj;
      const bool vl = (pwl >= 0), vr = (pwr <= NPW - 1);
      const int pwlc = vl ? pwl : 0;
      const int pwrc = vr ? pwr : NPW - 1;
      uint2 z00 = zb[((size_t)ph0c * NPW + pwlc) * 64 + l];
      uint2 z01 = zb[((size_t)ph0c * NPW + pwrc) * 64 + l];
      uint2 z10 = zb[((size_t)ph1c * NPW + pwlc) * 64 + l];
      uint2 z11 = zb[((size_t)ph1c * NPW + pwrc) * 64 + l];
      if (!(vh0 && vl)) { z00.x = 0u; z00.y = 0u; }
      if (!(vh0 && vr)) { z01.x = 0u; z01.y = 0u; }
      if (!(vh1 && vl)) { z10.x = 0u; z10.y = 0u; }
      if (!(vh1 && vr)) { z11.x = 0u; z11.y = 0u; }

      const float cntw = 2.0f - (cj == 0) - (cj == NCELL - 1);
      const float sc = 1.0f / (cnth * cntw);
      const float a0 = sc * (blo2f(z00.x) + blo2f(z01.x) + blo2f(z10.x) + blo2f(z11.x));
      const float a1 = sc * (bhi2f(z00.x) + bhi2f(z01.x) + bhi2f(z10.x) + bhi2f(z11.x));
      const float a2 = sc * (blo2f(z00.y) + blo2f(z01.y) + blo2f(z10.y) + blo2f(z11.y));
      const float a3 = sc * (bhi2f(z00.y) + bhi2f(z01.y) + bhi2f(z10.y) + bhi2f(z11.y));
      PW[cc * 132 + 16 * (2 * u)     + j] = pack2bf(a0, a1);
      PW[cc * 132 + 16 * (2 * u + 1) + j] = pack2bf(a2, a3);
    }
  }
  __syncthreads();

  // ---- phase B: x loads (after barrier), matvec with 32 uint4 LDS reads
  const float* xp = x + (size_t)bi * NCH * HW + (size_t)h * WDIM + wpx;
  float xv[16];
  #pragma unroll
  for (int e = 0; e < 16; ++e) xv[e] = xp[(size_t)e * HW];

  float acc[16];
  #pragma unroll
  for (int co = 0; co < 16; ++co) acc[co] = 0.f;
  #pragma unroll
  for (int p = 0; p < 8; ++p) {
    #pragma unroll
    for (int k = 0; k < 4; ++k) {
      const uint4 V = *(const uint4*)&PW[c * 132 + 16 * p + 4 * k];
      const unsigned int vv[4] = {V.x, V.y, V.z, V.w};
      #pragma unroll
      for (int e2 = 0; e2 < 4; ++e2) {
        const int e = 4 * k + e2;
        acc[2 * p]     += blo2f(vv[e2]) * xv[e];
        acc[2 * p + 1] += bhi2f(vv[e2]) * xv[e];
      }
    }
  }

  float* po = out + (size_t)bi * NCH * HW + (size_t)h * WDIM + wpx;
  #pragma unroll
  for (int co = 0; co < 16; ++co)
    po[(size_t)co * HW] = xv[co] - acc[co];    // scale pre-folded into W
}

extern "C" void kernel_launch(void* const* d_in, const int* in_sizes, int n_in,
                              void* d_out, int out_size, void* d_ws, size_t ws_size,
                              hipStream_t stream) {
  const float* x = (const float*)d_in[0];
  float* out = (float*)d_out;
  uint2* zs = (uint2*)d_ws;                    // 32258*512B = 16.5 MB

  llr_zs<<<dim3(ZS_NBLK), dim3(256), 0, stream>>>(x, zs);
  llr_q2<<<dim3(Q_NBLK), dim3(512), 0, stream>>>(x, zs, out);
}